// Round 18
// baseline (215.473 us; speedup 1.0000x reference)
//
#include <hip/hip_runtime.h>
#include <hip/hip_bf16.h>
#include <hip/hip_fp16.h>

// ---------------------------------------------------------------------------
// GraphAutoEncoder: 4x GCNConv + mean-pool + repeat.
// R1-R10: CSR build via LDS-binned buckets; fused layer kernels; zagg fusion.
// R11-R14: dec1v4 dense phases register-blocked; l1w2 in simple 68-VGPR form.
// R15: gathered feature tables fp16 (xh/t2h/t4h); f32 weights+accum.
// R16: l1w2 h1 LDS in fp16 (occupancy 24->30%); scatter reuses csr_off's scan.
// R17: EDGE-SPLIT gathers in l1w2/agg16h: 8 lanes/node = 4 feature lanes x
//      2 edge subgroups (alternating 4-edge chunks); partials merged via one
//      __shfl_xor(...,4). Halves the per-thread serial ew->gather chain,
//      doubles block count. (R16 showed l1w2 VALUBusy rises with waves.)
// ---------------------------------------------------------------------------

constexpr int BSZ_LOG = 9;                 // bucket = 512 dst nodes
constexpr int BSZ     = 1 << BSZ_LOG;
constexpr int NBMAX   = 256;               // max buckets (n <= 128K)
constexpr int ECHUNK  = 8192;              // edges per binfill block
constexpr int BCAP    = 12288;             // staging capacity per bucket
constexpr int ZSPLIT  = 8;                 // sub-blocks per bucket in zagg

struct alignas(8) h4 { __half2 a, b; };    // 4 halves = 8B

__device__ __forceinline__ float4 h4_to_f4(h4 v) {
    float2 fa = __half22float2(v.a), fb = __half22float2(v.b);
    return make_float4(fa.x, fa.y, fb.x, fb.y);
}

__device__ __forceinline__ int gdiv(int v, int npg, float inv) {
    int g = __float2int_rz((float)v * inv);
    int r = v - g * npg;
    if (r < 0) --g; else if (r >= npg) ++g;
    return g;
}

// Pass 1: LDS-binned bucket staging. code = (dst_local << 20) | src (src < 2^20).
__global__ __launch_bounds__(256)
void binfill_kernel(const int* __restrict__ src, const int* __restrict__ dst,
                    int* __restrict__ bcnt, int* __restrict__ binned, int E) {
    __shared__ int hist[NBMAX], hexcl[NBMAX], gbase[NBMAX], hpos[NBMAX], tmp[NBMAX];
    __shared__ int sorted[ECHUNK];
    __shared__ unsigned char bsorted[ECHUNK];
    int t = threadIdx.x;
    hist[t] = 0; hpos[t] = 0;
    __syncthreads();
    int e0 = blockIdx.x * ECHUNK;
    int cnt = min(ECHUNK, E - e0);
    for (int i = t; i < cnt; i += 256)
        atomicAdd(&hist[dst[e0 + i] >> BSZ_LOG], 1);
    __syncthreads();
    tmp[t] = hist[t];
    __syncthreads();
    for (int d = 1; d < 256; d <<= 1) {
        int v = (t >= d) ? tmp[t - d] : 0;
        __syncthreads();
        tmp[t] += v;
        __syncthreads();
    }
    hexcl[t] = (t == 0) ? 0 : tmp[t - 1];
    int h = hist[t];
    gbase[t] = (h > 0) ? atomicAdd(&bcnt[t], h) : 0;
    __syncthreads();
    for (int i = t; i < cnt; i += 256) {
        int s = src[e0 + i], d = dst[e0 + i];
        int b = d >> BSZ_LOG;
        int code = ((d & (BSZ - 1)) << 20) | s;
        int sp = hexcl[b] + atomicAdd(&hpos[b], 1);
        sorted[sp] = code;
        bsorted[sp] = (unsigned char)b;
    }
    __syncthreads();
    for (int i = t; i < cnt; i += 256) {
        int b = bsorted[i];
        binned[(size_t)b * BCAP + gbase[b] + (i - hexcl[b])] = sorted[i];
    }
}

// Block-reduce sum of bcnt[0..b) -> returned in sums[0] (all threads see it).
__device__ __forceinline__ int prefix_before(const int* __restrict__ bcnt,
                                             int b, int* sums) {
    int t = threadIdx.x;
    sums[t] = (t < b) ? bcnt[t] : 0;
    __syncthreads();
    for (int d = 128; d > 0; d >>= 1) {
        if (t < d) sums[t] += sums[t + d];
        __syncthreads();
    }
    int r = sums[0];
    __syncthreads();
    return r;
}

// Per bucket: LDS node histogram + scan -> off[]/dis[]; persists lstart/bstart.
__global__ __launch_bounds__(256)
void csr_off_kernel(const int* __restrict__ binned, const int* __restrict__ bcnt,
                    int* __restrict__ off, float* __restrict__ dis,
                    int* __restrict__ lstart_g, int* __restrict__ bstart_g,
                    int n, int E) {
    __shared__ int hist[BSZ];
    __shared__ int lstart[BSZ];
    __shared__ int partial[256];
    int b = blockIdx.x, t = threadIdx.x;
    int nb0 = b << BSZ_LOG;
    int nn = min(BSZ, n - nb0);
    int m = bcnt[b];
    int bs = prefix_before(bcnt, b, partial);
    const int* bp = binned + (size_t)b * BCAP;
    for (int i = t; i < BSZ; i += 256) hist[i] = 0;
    __syncthreads();
    for (int i = t; i < m; i += 256)
        atomicAdd(&hist[bp[i] >> 20], 1);
    __syncthreads();
    int a0 = hist[2 * t], a1 = hist[2 * t + 1];
    partial[t] = a0 + a1;
    __syncthreads();
    for (int d = 1; d < 256; d <<= 1) {
        int v = (t >= d) ? partial[t - d] : 0;
        __syncthreads();
        partial[t] += v;
        __syncthreads();
    }
    int base = (t == 0) ? 0 : partial[t - 1];
    lstart[2 * t] = base;
    lstart[2 * t + 1] = base + a0;
    __syncthreads();
    for (int i = t; i < BSZ; i += 256)
        lstart_g[(b << BSZ_LOG) + i] = lstart[i];
    for (int i = t; i < nn; i += 256) {
        off[nb0 + i] = bs + lstart[i];
        dis[nb0 + i] = rsqrtf((float)hist[i] + 1.0f);   // +1 = self-loop
    }
    if (t == 0) bstart_g[b] = bs;
    if (b == 0 && t == 0) off[n] = E;
}

// Per bucket: scatter {src | g<<20, w} using the persisted lstart/bstart.
__global__ __launch_bounds__(256)
void bucket_scatter_kernel(const int* __restrict__ binned, const int* __restrict__ bcnt,
                           const int* __restrict__ lstart_g, const int* __restrict__ bstart_g,
                           const float* __restrict__ dis,
                           const int* __restrict__ npg_p, int2* __restrict__ ew, int n) {
    __shared__ int lstart[BSZ];
    __shared__ int lpos[BSZ];
    __shared__ float ldis[BSZ];
    int b = blockIdx.x, t = threadIdx.x;
    int nb0 = b << BSZ_LOG;
    int nn = min(BSZ, n - nb0);
    int m = bcnt[b];
    int e0 = bstart_g[b];
    int npg = npg_p[0];
    float inv = 1.0f / (float)npg;
    const int* bp = binned + (size_t)b * BCAP;
    for (int i = t; i < BSZ; i += 256) {
        lstart[i] = lstart_g[(b << BSZ_LOG) + i];
        lpos[i] = 0;
        ldis[i] = (i < nn) ? dis[nb0 + i] : 0.f;
    }
    __syncthreads();
    for (int i = t; i < m; i += 256) {
        int code = bp[i];
        int dl = code >> 20, s = code & 0xFFFFF;
        float w = dis[s] * ldis[dl];
        int g = gdiv(s, npg, inv);
        int p = e0 + lstart[dl] + atomicAdd(&lpos[dl], 1);
        ew[p] = make_int2(s | (g << 20), __float_as_int(w));
    }
}

// x (f32, n x 16) -> xh (fp16). One float4 -> h4 per thread, grid-stride.
__global__ __launch_bounds__(256)
void xconv_kernel(const float* __restrict__ x, h4* __restrict__ xh, int n4) {
    const float4* xp = (const float4*)x;
    for (int i = blockIdx.x * 256 + threadIdx.x; i < n4; i += gridDim.x * 256) {
        float4 v = xp[i];
        h4 o;
        o.a = __floats2half2_rn(v.x, v.y);
        o.b = __floats2half2_rn(v.z, v.w);
        xh[i] = o;
    }
}

// ---- edge-split gather (fp16 table, 4 feature lanes x ES edge subgroups) --
// Each subgroup handles alternating 4-edge chunks; shfl width 4 broadcasts
// within the subgroup. Caller merges partials via __shfl_xor(...,4).
__device__ __forceinline__ float4
edge_loop_es(const h4* __restrict__ hp, const int2* __restrict__ ew,
             int e0, int e1, int q, int sub, float4 acc) {
    for (int base = e0 + sub * 4; base < e1; base += 8) {
        int idx = base + q;
        int2 a = (idx < e1) ? ew[idx] : make_int2(0, 0);
        int cnt = min(4, e1 - base);
#pragma unroll
        for (int k = 0; k < 4; ++k) {
            if (k < cnt) {
                int ax = __shfl(a.x, k, 4);
                float w = __int_as_float(__shfl(a.y, k, 4));
                int row = ax & 0xFFFFF;
                float4 v = h4_to_f4(hp[(size_t)row * 4 + q]);
                acc.x += w * v.x; acc.y += w * v.y; acc.z += w * v.z; acc.w += w * v.w;
            }
        }
    }
    return acc;
}

// f32-table variant (dec1v4's z gather), TPN lanes/node, shfl-broadcast.
template <int TPN, bool USE_G>
__device__ __forceinline__ float4
edge_loop(const float4* __restrict__ hp, const int2* __restrict__ ew,
          int e0, int e1, int q, float4 acc) {
    int deg = e1 - e0;
    int nfull = deg / TPN;
    int r = deg - nfull * TPN;
    int idx = e0 + q;
    int2 a = make_int2(0, 0);
    if (idx < e1) a = ew[idx];
    for (int c = 0; c < nfull; ++c) {
        int nidx = idx + (c + 1) * TPN;
        int2 an = make_int2(0, 0);
        if (nidx < e1) an = ew[nidx];
#pragma unroll
        for (int k = 0; k < TPN; ++k) {
            int ax = __shfl(a.x, k, TPN);
            float w = __int_as_float(__shfl(a.y, k, TPN));
            int row = USE_G ? (int)(((unsigned)ax) >> 20) : (ax & 0xFFFFF);
            float4 v = hp[(size_t)row * TPN + q];
            acc.x += w * v.x; acc.y += w * v.y; acc.z += w * v.z; acc.w += w * v.w;
        }
        a = an;
    }
    for (int k = 0; k < r; ++k) {
        int ax = __shfl(a.x, k, TPN);
        float w = __int_as_float(__shfl(a.y, k, TPN));
        int row = USE_G ? (int)(((unsigned)ax) >> 20) : (ax & 0xFFFFF);
        float4 v = hp[(size_t)row * TPN + q];
        acc.x += w * v.x; acc.y += w * v.y; acc.z += w * v.z; acc.w += w * v.w;
    }
    return acc;
}

// Layer 1 + W2 fused, edge-split: 8 lanes/node (4 feat x 2 edge subs),
// 32 nodes/block; partials merged via shfl_xor; h1 in fp16 LDS.
__global__ __launch_bounds__(256)
void l1w2_kernel(const h4* __restrict__ xh, const float* __restrict__ dis,
                 const int* __restrict__ off, const int2* __restrict__ ew,
                 const float* __restrict__ W1, const float* __restrict__ b1,
                 const float* __restrict__ W2, __half* __restrict__ t2h, int n) {
    __shared__ float accs[32][17];
    __shared__ __half2 hlh[32][33];
    __shared__ float Wl[16 * 64];
    __shared__ float bl[64];
    int t = threadIdx.x;
    for (int i = t; i < 16 * 64; i += 256) Wl[i] = W1[i];
    if (t < 64) bl[t] = b1[t];

    int q = t & 3, sub = (t >> 2) & 1, ln = t >> 3;
    int node = blockIdx.x * 32 + ln;
    float4 acc = make_float4(0.f, 0.f, 0.f, 0.f);
    if (node < n) {
        int e0 = off[node], e1 = off[node + 1];
        if (sub == 0) {
            float di = dis[node], d2 = di * di;
            float4 v = h4_to_f4(xh[(size_t)node * 4 + q]);
            acc.x = d2 * v.x; acc.y = d2 * v.y; acc.z = d2 * v.z; acc.w = d2 * v.w;
        }
        acc = edge_loop_es(xh, ew, e0, e1, q, sub, acc);
    }
    // merge the two edge-subgroup partials (lane t <-> t^4)
    acc.x += __shfl_xor(acc.x, 4);
    acc.y += __shfl_xor(acc.y, 4);
    acc.z += __shfl_xor(acc.z, 4);
    acc.w += __shfl_xor(acc.w, 4);
    if (sub == 0) {
        accs[ln][q * 4 + 0] = acc.x; accs[ln][q * 4 + 1] = acc.y;
        accs[ln][q * 4 + 2] = acc.z; accs[ln][q * 4 + 3] = acc.w;
    }
    __syncthreads();

    // Phase B: h1 row (64-wide) into fp16 LDS.
    int j = t & 63;
    for (int nb = (t >> 6); nb < 32; nb += 4) {
        float s = bl[j];
#pragma unroll
        for (int k = 0; k < 16; ++k) s += accs[nb][k] * Wl[k * 64 + j];
        ((__half*)hlh[nb])[j] = __float2half(fmaxf(s, 0.f));
    }
    __syncthreads();

    // Phase C: t2h[node][c] = h1 . W2[:,c]
    int base = blockIdx.x * 32;
    int c = t & 31;
    for (int nb = (t >> 5); nb < 32; nb += 8) {
        int nd = base + nb;
        if (nd >= n) break;
        float s = 0.f;
#pragma unroll
        for (int k = 0; k < 32; ++k) {
            float2 hp = __half22float2(hlh[nb][k]);
            s += hp.x * W2[(2 * k) * 32 + c] + hp.y * W2[(2 * k + 1) * 32 + c];
        }
        t2h[(size_t)nd * 32 + c] = __float2half(s);
    }
}

// Final aggregate, edge-split: 8 lanes/node, t4h fp16 gather, f32 out.
__global__ __launch_bounds__(256)
void agg16h_kernel(const h4* __restrict__ t4h, const float* __restrict__ dis,
                   const int* __restrict__ off, const int2* __restrict__ ew,
                   const float* __restrict__ b, float* __restrict__ out, int n) {
    int t = threadIdx.x;
    int q = t & 3, sub = (t >> 2) & 1, ln = t >> 3;
    int node = blockIdx.x * 32 + ln;
    if (node >= n) return;   // safe: t and t^4 share ln -> both return
    int e0 = off[node], e1 = off[node + 1];
    float4 acc = make_float4(0.f, 0.f, 0.f, 0.f);
    if (sub == 0) {
        float di = dis[node], d2 = di * di;
        float4 v = h4_to_f4(t4h[(size_t)node * 4 + q]);
        acc.x = d2 * v.x; acc.y = d2 * v.y; acc.z = d2 * v.z; acc.w = d2 * v.w;
    }
    acc = edge_loop_es(t4h, ew, e0, e1, q, sub, acc);
    acc.x += __shfl_xor(acc.x, 4);
    acc.y += __shfl_xor(acc.y, 4);
    acc.z += __shfl_xor(acc.z, 4);
    acc.w += __shfl_xor(acc.w, 4);
    if (sub == 0) {
        float4 bb = ((const float4*)b)[q];
        float4 o;
        o.x = acc.x + bb.x; o.y = acc.y + bb.y; o.z = acc.z + bb.z; o.w = acc.w + bb.w;
        ((float4*)out)[(size_t)node * 4 + q] = o;
    }
}

// zagg: per (bucket, split): accumulate z-sums edge-major from t2h (fp16).
__global__ __launch_bounds__(256)
void zagg_kernel(const h4* __restrict__ t2h, const float* __restrict__ dis,
                 const int* __restrict__ off, const int2* __restrict__ ew,
                 const int* __restrict__ npg_p, float* __restrict__ zsum, int n) {
    __shared__ float4 red0[256];
    __shared__ float4 red1[256];
    int blk = blockIdx.x;
    int b = blk / ZSPLIT, s = blk % ZSPLIT;
    int t = threadIdx.x, q = t & 7, r = t >> 3;
    int npg = npg_p[0];
    int nb0 = b << BSZ_LOG;
    int nn = min(BSZ, n - nb0);
    int g0 = nb0 / npg;
    int nodeB = min((g0 + 1) * npg - nb0, nn);   // local boundary node
    int e0 = off[nb0], e1 = off[nb0 + nn];
    int P  = off[nb0 + nodeB];
    int m = e1 - e0;

    float4 a0 = make_float4(0.f, 0.f, 0.f, 0.f);
    float4 a1 = make_float4(0.f, 0.f, 0.f, 0.f);
    int i0 = (int)((long long)m * s / ZSPLIT);
    int i1 = (int)((long long)m * (s + 1) / ZSPLIT);
    for (int i = i0 + r; i < i1; i += 32) {
        int e = e0 + i;
        int2 aa = ew[e];
        float w = __int_as_float(aa.y);
        int src = aa.x & 0xFFFFF;
        float4 v = h4_to_f4(t2h[(size_t)src * 8 + q]);
        if (e < P) {
            a0.x += w * v.x; a0.y += w * v.y; a0.z += w * v.z; a0.w += w * v.w;
        } else {
            a1.x += w * v.x; a1.y += w * v.y; a1.z += w * v.z; a1.w += w * v.w;
        }
    }
    int j0 = nn * s / ZSPLIT, j1 = nn * (s + 1) / ZSPLIT;
    for (int i = j0 + r; i < j1; i += 32) {
        int node = nb0 + i;
        float di = dis[node], d2 = di * di;
        float4 v = h4_to_f4(t2h[(size_t)node * 8 + q]);
        if (i < nodeB) {
            a0.x += d2 * v.x; a0.y += d2 * v.y; a0.z += d2 * v.z; a0.w += d2 * v.w;
        } else {
            a1.x += d2 * v.x; a1.y += d2 * v.y; a1.z += d2 * v.z; a1.w += d2 * v.w;
        }
    }
    red0[t] = a0; red1[t] = a1;
    __syncthreads();
    for (int d = 128; d >= 8; d >>= 1) {
        if (t < d) {
            float4 u = red0[t], v = red0[t + d];
            u.x += v.x; u.y += v.y; u.z += v.z; u.w += v.w;
            red0[t] = u;
            u = red1[t]; v = red1[t + d];
            u.x += v.x; u.y += v.y; u.z += v.z; u.w += v.w;
            red1[t] = u;
        }
        __syncthreads();
    }
    if (t < 8) {
        float4 v = red0[t];
        atomicAdd(&zsum[g0 * 32 + t * 4 + 0], v.x);
        atomicAdd(&zsum[g0 * 32 + t * 4 + 1], v.y);
        atomicAdd(&zsum[g0 * 32 + t * 4 + 2], v.z);
        atomicAdd(&zsum[g0 * 32 + t * 4 + 3], v.w);
    } else if (t < 16 && nodeB < nn) {
        float4 v = red1[t - 8];
        atomicAdd(&zsum[(g0 + 1) * 32 + (t - 8) * 4 + 0], v.x);
        atomicAdd(&zsum[(g0 + 1) * 32 + (t - 8) * 4 + 1], v.y);
        atomicAdd(&zsum[(g0 + 1) * 32 + (t - 8) * 4 + 2], v.z);
        atomicAdd(&zsum[(g0 + 1) * 32 + (t - 8) * 4 + 3], v.w);
    }
}

// z[g][c] = zsum[g][c]/npg + b2[c]
__global__ __launch_bounds__(256)
void zred_kernel(const float* __restrict__ zsum, const float* __restrict__ b2,
                 const int* __restrict__ npg_p, float* __restrict__ Z, int n) {
    int npg = npg_p[0];
    int G = n / npg;
    float inv = 1.0f / (float)npg;
    for (int i = blockIdx.x * 256 + threadIdx.x; i < G * 32; i += gridDim.x * 256)
        Z[i] = zsum[i] * inv + b2[i & 31];
}

// Decoder fused: aggregate 32-wide z rows (f32, L1-resident); dense phases
// register-blocked; writes t4h (fp16) for the final aggregation.
__global__ __launch_bounds__(256)
void dec1v4_kernel(const float* __restrict__ Z, const float* __restrict__ dis,
                   const int* __restrict__ off, const int2* __restrict__ ew,
                   const int* __restrict__ npg_p, const float* __restrict__ W3,
                   const float* __restrict__ b3, const float* __restrict__ W4,
                   __half* __restrict__ t4h, int n) {
    __shared__ float zacc[32 * 36];   // stride 36 (float4-aligned)
    __shared__ float hl[32 * 68];     // stride 68 (float4-aligned)
    int t = threadIdx.x;
    int npg = npg_p[0];
    float inv = 1.0f / (float)npg;
    int q = t & 7, ln = t >> 3;          // 8 lanes/node, 32 nodes/block
    int base = blockIdx.x * 32;
    int node = base + ln;
    const float4* zp = (const float4*)Z;

    float4 acc = make_float4(0.f, 0.f, 0.f, 0.f);
    if (node < n) {
        float di = dis[node], d2 = di * di;
        int gi = gdiv(node, npg, inv);
        float4 v = zp[(size_t)gi * 8 + q];
        acc.x = d2 * v.x; acc.y = d2 * v.y; acc.z = d2 * v.z; acc.w = d2 * v.w;
        acc = edge_loop<8, true>(zp, ew, off[node], off[node + 1], q, acc);
    }
    zacc[ln * 36 + q * 4 + 0] = acc.x;
    zacc[ln * 36 + q * 4 + 1] = acc.y;
    zacc[ln * 36 + q * 4 + 2] = acc.z;
    zacc[ln * 36 + q * 4 + 3] = acc.w;
    __syncthreads();

    // B1: h = relu(zacc @ W3 + b3). 64 cols x 4 row-groups of 8 nodes.
    {
        int j = t & 63;
        int i0 = (t >> 6) * 8;
        float w3c[32];
#pragma unroll
        for (int k = 0; k < 32; ++k) w3c[k] = W3[k * 64 + j];
        float bj = b3[j];
        const float4* za4 = (const float4*)zacc;
#pragma unroll
        for (int ii = 0; ii < 8; ++ii) {
            int i = i0 + ii;
            float s = bj;
#pragma unroll
            for (int m = 0; m < 8; ++m) {
                float4 zv = za4[i * 9 + m];
                s += zv.x * w3c[4 * m] + zv.y * w3c[4 * m + 1]
                   + zv.z * w3c[4 * m + 2] + zv.w * w3c[4 * m + 3];
            }
            hl[i * 68 + j] = fmaxf(s, 0.f);
        }
    }
    __syncthreads();

    // B2: t4h = hl @ W4 (64->16), fp16 store. 16 cols x 16 rows; 2 nodes/thread.
    {
        int c = t & 15;
        int i0 = t >> 4;
        int i1 = i0 + 16;
        const float4* hl4 = (const float4*)hl;
        float s0 = 0.f, s1 = 0.f;
#pragma unroll
        for (int kh = 0; kh < 2; ++kh) {
            float w4c[32];
#pragma unroll
            for (int k = 0; k < 32; ++k) w4c[k] = W4[(kh * 32 + k) * 16 + c];
#pragma unroll
            for (int m = 0; m < 8; ++m) {
                float4 h0 = hl4[i0 * 17 + kh * 8 + m];
                float4 h1 = hl4[i1 * 17 + kh * 8 + m];
                s0 += h0.x * w4c[4 * m] + h0.y * w4c[4 * m + 1]
                    + h0.z * w4c[4 * m + 2] + h0.w * w4c[4 * m + 3];
                s1 += h1.x * w4c[4 * m] + h1.y * w4c[4 * m + 1]
                    + h1.z * w4c[4 * m + 2] + h1.w * w4c[4 * m + 3];
            }
        }
        int nd0 = base + i0, nd1 = base + i1;
        if (nd0 < n) t4h[(size_t)nd0 * 16 + c] = __float2half(s0);
        if (nd1 < n) t4h[(size_t)nd1 * 16 + c] = __float2half(s1);
    }
}

extern "C" void kernel_launch(void* const* d_in, const int* in_sizes, int n_in,
                              void* d_out, int out_size, void* d_ws, size_t ws_size,
                              hipStream_t stream) {
    const float* x     = (const float*)d_in[0];
    const int*   ei    = (const int*)d_in[1];
    const int*   npg   = (const int*)d_in[3];
    const float* W1 = (const float*)d_in[4];
    const float* b1 = (const float*)d_in[5];
    const float* W2 = (const float*)d_in[6];
    const float* b2 = (const float*)d_in[7];
    const float* W3 = (const float*)d_in[8];
    const float* b3 = (const float*)d_in[9];
    const float* W4 = (const float*)d_in[10];
    const float* b4 = (const float*)d_in[11];
    float* out = (float*)d_out;

    int n = in_sizes[0] / 16;
    int E = in_sizes[1] / 2;
    const int* srcp = ei;
    const int* dstp = ei + E;

    char* w = (char*)d_ws;
    auto alloc = [&](size_t bytes) {
        char* p = w;
        w += (bytes + 255) & ~(size_t)255;
        return p;
    };
    float*  dis      = (float*)alloc((size_t)n * 4);
    int*    off      = (int*)alloc(((size_t)n + 1) * 4);
    int*    binned   = (int*)alloc((size_t)NBMAX * BCAP * 4);
    int2*   ew       = (int2*)alloc((size_t)E * 8);
    h4*     xh       = (h4*)alloc((size_t)n * 16 * 2);
    __half* t2h      = (__half*)alloc((size_t)n * 32 * 2);
    __half* t4h      = (__half*)alloc((size_t)n * 16 * 2);
    float*  Z        = (float*)alloc((size_t)4096 * 32 * 4);
    float*  zsum     = (float*)alloc((size_t)4096 * 32 * 4);
    int*    bcnt     = (int*)alloc((size_t)NBMAX * 4);
    int*    lstart_g = (int*)alloc((size_t)NBMAX * BSZ * 4);
    int*    bstart_g = (int*)alloc((size_t)NBMAX * 4);

    int nbuck = (n + BSZ - 1) / BSZ;
    int nbin  = (E + ECHUNK - 1) / ECHUNK;

    // ---- CSR build + fp16 x table ----
    hipMemsetAsync(bcnt, 0, (size_t)NBMAX * 4, stream);
    hipMemsetAsync(zsum, 0, (size_t)4096 * 32 * 4, stream);
    xconv_kernel<<<512, 256, 0, stream>>>(x, xh, n * 4);
    binfill_kernel<<<nbin, 256, 0, stream>>>(srcp, dstp, bcnt, binned, E);
    csr_off_kernel<<<nbuck, 256, 0, stream>>>(binned, bcnt, off, dis, lstart_g, bstart_g, n, E);
    bucket_scatter_kernel<<<nbuck, 256, 0, stream>>>(binned, bcnt, lstart_g, bstart_g, dis, npg, ew, n);

    // encode
    l1w2_kernel<<<(n + 31) / 32, 256, 0, stream>>>(xh, dis, off, ew, W1, b1, W2, t2h, n);
    zagg_kernel<<<nbuck * ZSPLIT, 256, 0, stream>>>((const h4*)t2h, dis, off, ew, npg, zsum, n);
    zred_kernel<<<16, 256, 0, stream>>>(zsum, b2, npg, Z, n);

    // decode
    dec1v4_kernel<<<(n + 31) / 32, 256, 0, stream>>>(Z, dis, off, ew, npg, W3, b3, W4, t4h, n);
    agg16h_kernel<<<(n + 31) / 32, 256, 0, stream>>>((const h4*)t4h, dis, off, ew, b4, out, n);
}

// Round 19
// 211.864 us; speedup vs baseline: 1.0170x; 1.0170x over previous
//
#include <hip/hip_runtime.h>
#include <hip/hip_bf16.h>
#include <hip/hip_fp16.h>

// ---------------------------------------------------------------------------
// GraphAutoEncoder: 4x GCNConv + mean-pool + repeat.
// R1-R10: bucket CSR build; fused layers; zagg fusion. R11-R14: dec1v4 dense
// phases register-blocked; l1w2 simple form. R15: fp16 gather tables.
// R16: fp16 h1 LDS; scatter reuses csr_off's scan. R17: edge-split REGRESSED
//      (dropped prefetch pipeline) -> reverted.
// R18: WEIGHT FACTORIZATION. w_e = dis_src*dis_dst and tables stored
//      pre-scaled by dis (xs=dis*x etc), so:
//        agg(node) = dis[node] * (sum_e table[src_e] + table[node])
//      l1w2/agg16h: NO per-edge weight -> ew is 4B (src|g<<20), edge stream
//      halved. dec1v4: + fp16 diss[e]=dis[src]. zagg: + fp16 disw[e]=dis[dst].
// ---------------------------------------------------------------------------

constexpr int BSZ_LOG = 9;                 // bucket = 512 dst nodes
constexpr int BSZ     = 1 << BSZ_LOG;
constexpr int NBMAX   = 256;               // max buckets (n <= 128K)
constexpr int ECHUNK  = 8192;              // edges per binfill block
constexpr int BCAP    = 12288;             // staging capacity per bucket
constexpr int ZSPLIT  = 8;                 // sub-blocks per bucket in zagg

struct alignas(8) h4 { __half2 a, b; };    // 4 halves = 8B

__device__ __forceinline__ float4 h4_to_f4(h4 v) {
    float2 fa = __half22float2(v.a), fb = __half22float2(v.b);
    return make_float4(fa.x, fa.y, fb.x, fb.y);
}

__device__ __forceinline__ int gdiv(int v, int npg, float inv) {
    int g = __float2int_rz((float)v * inv);
    int r = v - g * npg;
    if (r < 0) --g; else if (r >= npg) ++g;
    return g;
}

// Pass 1: LDS-binned bucket staging. code = (dst_local << 20) | src (src < 2^20).
__global__ __launch_bounds__(256)
void binfill_kernel(const int* __restrict__ src, const int* __restrict__ dst,
                    int* __restrict__ bcnt, int* __restrict__ binned, int E) {
    __shared__ int hist[NBMAX], hexcl[NBMAX], gbase[NBMAX], hpos[NBMAX], tmp[NBMAX];
    __shared__ int sorted[ECHUNK];
    __shared__ unsigned char bsorted[ECHUNK];
    int t = threadIdx.x;
    hist[t] = 0; hpos[t] = 0;
    __syncthreads();
    int e0 = blockIdx.x * ECHUNK;
    int cnt = min(ECHUNK, E - e0);
    for (int i = t; i < cnt; i += 256)
        atomicAdd(&hist[dst[e0 + i] >> BSZ_LOG], 1);
    __syncthreads();
    tmp[t] = hist[t];
    __syncthreads();
    for (int d = 1; d < 256; d <<= 1) {
        int v = (t >= d) ? tmp[t - d] : 0;
        __syncthreads();
        tmp[t] += v;
        __syncthreads();
    }
    hexcl[t] = (t == 0) ? 0 : tmp[t - 1];
    int h = hist[t];
    gbase[t] = (h > 0) ? atomicAdd(&bcnt[t], h) : 0;
    __syncthreads();
    for (int i = t; i < cnt; i += 256) {
        int s = src[e0 + i], d = dst[e0 + i];
        int b = d >> BSZ_LOG;
        int code = ((d & (BSZ - 1)) << 20) | s;
        int sp = hexcl[b] + atomicAdd(&hpos[b], 1);
        sorted[sp] = code;
        bsorted[sp] = (unsigned char)b;
    }
    __syncthreads();
    for (int i = t; i < cnt; i += 256) {
        int b = bsorted[i];
        binned[(size_t)b * BCAP + gbase[b] + (i - hexcl[b])] = sorted[i];
    }
}

// Block-reduce sum of bcnt[0..b) -> returned in sums[0].
__device__ __forceinline__ int prefix_before(const int* __restrict__ bcnt,
                                             int b, int* sums) {
    int t = threadIdx.x;
    sums[t] = (t < b) ? bcnt[t] : 0;
    __syncthreads();
    for (int d = 128; d > 0; d >>= 1) {
        if (t < d) sums[t] += sums[t + d];
        __syncthreads();
    }
    int r = sums[0];
    __syncthreads();
    return r;
}

// Per bucket: LDS node histogram + scan -> off[]/dis[]; persists lstart/bstart.
__global__ __launch_bounds__(256)
void csr_off_kernel(const int* __restrict__ binned, const int* __restrict__ bcnt,
                    int* __restrict__ off, float* __restrict__ dis,
                    int* __restrict__ lstart_g, int* __restrict__ bstart_g,
                    int n, int E) {
    __shared__ int hist[BSZ];
    __shared__ int lstart[BSZ];
    __shared__ int partial[256];
    int b = blockIdx.x, t = threadIdx.x;
    int nb0 = b << BSZ_LOG;
    int nn = min(BSZ, n - nb0);
    int m = bcnt[b];
    int bs = prefix_before(bcnt, b, partial);
    const int* bp = binned + (size_t)b * BCAP;
    for (int i = t; i < BSZ; i += 256) hist[i] = 0;
    __syncthreads();
    for (int i = t; i < m; i += 256)
        atomicAdd(&hist[bp[i] >> 20], 1);
    __syncthreads();
    int a0 = hist[2 * t], a1 = hist[2 * t + 1];
    partial[t] = a0 + a1;
    __syncthreads();
    for (int d = 1; d < 256; d <<= 1) {
        int v = (t >= d) ? partial[t - d] : 0;
        __syncthreads();
        partial[t] += v;
        __syncthreads();
    }
    int base = (t == 0) ? 0 : partial[t - 1];
    lstart[2 * t] = base;
    lstart[2 * t + 1] = base + a0;
    __syncthreads();
    for (int i = t; i < BSZ; i += 256)
        lstart_g[(b << BSZ_LOG) + i] = lstart[i];
    for (int i = t; i < nn; i += 256) {
        off[nb0 + i] = bs + lstart[i];
        dis[nb0 + i] = rsqrtf((float)hist[i] + 1.0f);   // +1 = self-loop
    }
    if (t == 0) bstart_g[b] = bs;
    if (b == 0 && t == 0) off[n] = E;
}

// Per bucket: scatter {src|g<<20} + fp16 dis[src]/dis[dst] per edge.
__global__ __launch_bounds__(256)
void bucket_scatter_kernel(const int* __restrict__ binned, const int* __restrict__ bcnt,
                           const int* __restrict__ lstart_g, const int* __restrict__ bstart_g,
                           const float* __restrict__ dis,
                           const int* __restrict__ npg_p, int* __restrict__ ew4,
                           __half* __restrict__ diss, __half* __restrict__ disw, int n) {
    __shared__ int lstart[BSZ];
    __shared__ int lpos[BSZ];
    __shared__ float ldis[BSZ];
    int b = blockIdx.x, t = threadIdx.x;
    int nb0 = b << BSZ_LOG;
    int nn = min(BSZ, n - nb0);
    int m = bcnt[b];
    int e0 = bstart_g[b];
    int npg = npg_p[0];
    float inv = 1.0f / (float)npg;
    const int* bp = binned + (size_t)b * BCAP;
    for (int i = t; i < BSZ; i += 256) {
        lstart[i] = lstart_g[(b << BSZ_LOG) + i];
        lpos[i] = 0;
        ldis[i] = (i < nn) ? dis[nb0 + i] : 0.f;
    }
    __syncthreads();
    for (int i = t; i < m; i += 256) {
        int code = bp[i];
        int dl = code >> 20, s = code & 0xFFFFF;
        int g = gdiv(s, npg, inv);
        int p = e0 + lstart[dl] + atomicAdd(&lpos[dl], 1);
        ew4[p]  = s | (g << 20);
        diss[p] = __float2half(dis[s]);
        disw[p] = __float2half(ldis[dl]);
    }
}

// x (f32, n x 16) -> xs (fp16, PRE-SCALED by dis[node]).
__global__ __launch_bounds__(256)
void xconv_kernel(const float* __restrict__ x, const float* __restrict__ dis,
                  h4* __restrict__ xh, int n4) {
    const float4* xp = (const float4*)x;
    for (int i = blockIdx.x * 256 + threadIdx.x; i < n4; i += gridDim.x * 256) {
        float d = dis[i >> 2];
        float4 v = xp[i];
        h4 o;
        o.a = __floats2half2_rn(d * v.x, d * v.y);
        o.b = __floats2half2_rn(d * v.z, d * v.w);
        xh[i] = o;
    }
}

// ---- unweighted shfl-broadcast gather over fp16 table (TPN lanes/node) ----
// Prefetched (R8/R16 pipeline). row = ax & 0xFFFFF. No per-edge weight.
template <int TPN>
__device__ __forceinline__ float4
edge_loop_ns(const h4* __restrict__ hp, const int* __restrict__ ew4,
             int e0, int e1, int q, float4 acc) {
    int deg = e1 - e0;
    int nfull = deg / TPN;
    int r = deg - nfull * TPN;
    int idx = e0 + q;
    int a = (idx < e1) ? ew4[idx] : 0;
    for (int c = 0; c < nfull; ++c) {
        int nidx = idx + (c + 1) * TPN;
        int an = (nidx < e1) ? ew4[nidx] : 0;
#pragma unroll
        for (int k = 0; k < TPN; ++k) {
            int ax = __shfl(a, k, TPN);
            int row = ax & 0xFFFFF;
            float4 v = h4_to_f4(hp[(size_t)row * TPN + q]);
            acc.x += v.x; acc.y += v.y; acc.z += v.z; acc.w += v.w;
        }
        a = an;
    }
    for (int k = 0; k < r; ++k) {
        int ax = __shfl(a, k, TPN);
        int row = ax & 0xFFFFF;
        float4 v = h4_to_f4(hp[(size_t)row * TPN + q]);
        acc.x += v.x; acc.y += v.y; acc.z += v.z; acc.w += v.w;
    }
    return acc;
}

// dec1's z gather: table keyed by g = ax>>20, weighted by fp16 dis[src].
__device__ __forceinline__ float4
zedge_loop(const float4* __restrict__ zp, const int* __restrict__ ew4,
           const __half* __restrict__ diss, int e0, int e1, int q, float4 acc) {
    int deg = e1 - e0;
    int nfull = deg / 8;
    int r = deg - nfull * 8;
    int idx = e0 + q;
    int a = 0; float wq = 0.f;
    if (idx < e1) { a = ew4[idx]; wq = __half2float(diss[idx]); }
    for (int c = 0; c < nfull; ++c) {
        int nidx = idx + (c + 1) * 8;
        int an = 0; float wn = 0.f;
        if (nidx < e1) { an = ew4[nidx]; wn = __half2float(diss[nidx]); }
#pragma unroll
        for (int k = 0; k < 8; ++k) {
            int ax = __shfl(a, k, 8);
            float w = __shfl(wq, k, 8);
            int g = (int)(((unsigned)ax) >> 20);
            float4 v = zp[(size_t)g * 8 + q];
            acc.x += w * v.x; acc.y += w * v.y; acc.z += w * v.z; acc.w += w * v.w;
        }
        a = an; wq = wn;
    }
    for (int k = 0; k < r; ++k) {
        int ax = __shfl(a, k, 8);
        float w = __shfl(wq, k, 8);
        int g = (int)(((unsigned)ax) >> 20);
        float4 v = zp[(size_t)g * 8 + q];
        acc.x += w * v.x; acc.y += w * v.y; acc.z += w * v.z; acc.w += w * v.w;
    }
    return acc;
}

// Layer 1 + W2 fused: unweighted gather of xs; acc *= dis[node]; phase-B h1
// (fp16 LDS); phase-C t2h = fp16(dis[nd] * h1.W2) — pre-scaled for next layer.
__global__ __launch_bounds__(256)
void l1w2_kernel(const h4* __restrict__ xh, const float* __restrict__ dis,
                 const int* __restrict__ off, const int* __restrict__ ew4,
                 const float* __restrict__ W1, const float* __restrict__ b1,
                 const float* __restrict__ W2, __half* __restrict__ t2h, int n) {
    __shared__ float accs[64][17];
    __shared__ __half2 hlh[64][33];
    __shared__ float Wl[16 * 64];
    __shared__ float bl[64];
    int t = threadIdx.x;
    for (int i = t; i < 16 * 64; i += 256) Wl[i] = W1[i];
    if (t < 64) bl[t] = b1[t];

    int q = t & 3, ln = t >> 2;
    int node = blockIdx.x * 64 + ln;
    float4 acc = make_float4(0.f, 0.f, 0.f, 0.f);
    if (node < n) {
        float dnode = dis[node];
        float4 v = h4_to_f4(xh[(size_t)node * 4 + q]);   // xs[node] (self term)
        acc.x = v.x; acc.y = v.y; acc.z = v.z; acc.w = v.w;
        acc = edge_loop_ns<4>(xh, ew4, off[node], off[node + 1], q, acc);
        acc.x *= dnode; acc.y *= dnode; acc.z *= dnode; acc.w *= dnode;
    }
    accs[ln][q * 4 + 0] = acc.x; accs[ln][q * 4 + 1] = acc.y;
    accs[ln][q * 4 + 2] = acc.z; accs[ln][q * 4 + 3] = acc.w;
    __syncthreads();

    // Phase B: h1 row (64-wide) into fp16 LDS
    int j = t & 63;
    for (int nb = (t >> 6); nb < 64; nb += 4) {
        float s = bl[j];
#pragma unroll
        for (int k = 0; k < 16; ++k) s += accs[nb][k] * Wl[k * 64 + j];
        ((__half*)hlh[nb])[j] = __float2half(fmaxf(s, 0.f));
    }
    __syncthreads();

    // Phase C: t2h[node][c] = dis[node] * (h1 . W2[:,c])
    int base = blockIdx.x * 64;
    int c = t & 31;
    for (int nb = (t >> 5); nb < 64; nb += 8) {
        int nd = base + nb;
        if (nd >= n) break;
        float s = 0.f;
#pragma unroll
        for (int k = 0; k < 32; ++k) {
            float2 hp = __half22float2(hlh[nb][k]);
            s += hp.x * W2[(2 * k) * 32 + c] + hp.y * W2[(2 * k + 1) * 32 + c];
        }
        t2h[(size_t)nd * 32 + c] = __float2half(dis[nd] * s);
    }
}

// Final aggregate: unweighted gather of ts4; out = dis[node]*acc + b4 (f32).
__global__ __launch_bounds__(256)
void agg16h_kernel(const h4* __restrict__ t4h, const float* __restrict__ dis,
                   const int* __restrict__ off, const int* __restrict__ ew4,
                   const float* __restrict__ b, float* __restrict__ out, int n) {
    int t = threadIdx.x;
    int q = t & 3, ln = t >> 2;
    int node = blockIdx.x * 64 + ln;
    if (node >= n) return;
    float dnode = dis[node];
    float4 v = h4_to_f4(t4h[(size_t)node * 4 + q]);   // ts4[node] (self term)
    float4 acc;
    acc.x = v.x; acc.y = v.y; acc.z = v.z; acc.w = v.w;
    acc = edge_loop_ns<4>(t4h, ew4, off[node], off[node + 1], q, acc);
    float4 bb = ((const float4*)b)[q];
    float4 o;
    o.x = dnode * acc.x + bb.x; o.y = dnode * acc.y + bb.y;
    o.z = dnode * acc.z + bb.z; o.w = dnode * acc.w + bb.w;
    ((float4*)out)[(size_t)node * 4 + q] = o;
}

// zagg: edge-major z-sums from ts2 (fp16, pre-scaled by dis[src]); per-edge
// weight = fp16 dis[dst] (disw). Self term: dis[node]*ts2[node].
__global__ __launch_bounds__(256)
void zagg_kernel(const h4* __restrict__ t2h, const float* __restrict__ dis,
                 const int* __restrict__ off, const int* __restrict__ ew4,
                 const __half* __restrict__ disw,
                 const int* __restrict__ npg_p, float* __restrict__ zsum, int n) {
    __shared__ float4 red0[256];
    __shared__ float4 red1[256];
    int blk = blockIdx.x;
    int b = blk / ZSPLIT, s = blk % ZSPLIT;
    int t = threadIdx.x, q = t & 7, r = t >> 3;
    int npg = npg_p[0];
    int nb0 = b << BSZ_LOG;
    int nn = min(BSZ, n - nb0);
    int g0 = nb0 / npg;
    int nodeB = min((g0 + 1) * npg - nb0, nn);   // local boundary node
    int e0 = off[nb0], e1 = off[nb0 + nn];
    int P  = off[nb0 + nodeB];
    int m = e1 - e0;

    float4 a0 = make_float4(0.f, 0.f, 0.f, 0.f);
    float4 a1 = make_float4(0.f, 0.f, 0.f, 0.f);
    int i0 = (int)((long long)m * s / ZSPLIT);
    int i1 = (int)((long long)m * (s + 1) / ZSPLIT);
    for (int i = i0 + r; i < i1; i += 32) {
        int e = e0 + i;
        int ax = ew4[e];
        float w = __half2float(disw[e]);
        int src = ax & 0xFFFFF;
        float4 v = h4_to_f4(t2h[(size_t)src * 8 + q]);
        if (e < P) {
            a0.x += w * v.x; a0.y += w * v.y; a0.z += w * v.z; a0.w += w * v.w;
        } else {
            a1.x += w * v.x; a1.y += w * v.y; a1.z += w * v.z; a1.w += w * v.w;
        }
    }
    int j0 = nn * s / ZSPLIT, j1 = nn * (s + 1) / ZSPLIT;
    for (int i = j0 + r; i < j1; i += 32) {
        int node = nb0 + i;
        float d = dis[node];
        float4 v = h4_to_f4(t2h[(size_t)node * 8 + q]);
        if (i < nodeB) {
            a0.x += d * v.x; a0.y += d * v.y; a0.z += d * v.z; a0.w += d * v.w;
        } else {
            a1.x += d * v.x; a1.y += d * v.y; a1.z += d * v.z; a1.w += d * v.w;
        }
    }
    red0[t] = a0; red1[t] = a1;
    __syncthreads();
    for (int d = 128; d >= 8; d >>= 1) {
        if (t < d) {
            float4 u = red0[t], v = red0[t + d];
            u.x += v.x; u.y += v.y; u.z += v.z; u.w += v.w;
            red0[t] = u;
            u = red1[t]; v = red1[t + d];
            u.x += v.x; u.y += v.y; u.z += v.z; u.w += v.w;
            red1[t] = u;
        }
        __syncthreads();
    }
    if (t < 8) {
        float4 v = red0[t];
        atomicAdd(&zsum[g0 * 32 + t * 4 + 0], v.x);
        atomicAdd(&zsum[g0 * 32 + t * 4 + 1], v.y);
        atomicAdd(&zsum[g0 * 32 + t * 4 + 2], v.z);
        atomicAdd(&zsum[g0 * 32 + t * 4 + 3], v.w);
    } else if (t < 16 && nodeB < nn) {
        float4 v = red1[t - 8];
        atomicAdd(&zsum[(g0 + 1) * 32 + (t - 8) * 4 + 0], v.x);
        atomicAdd(&zsum[(g0 + 1) * 32 + (t - 8) * 4 + 1], v.y);
        atomicAdd(&zsum[(g0 + 1) * 32 + (t - 8) * 4 + 2], v.z);
        atomicAdd(&zsum[(g0 + 1) * 32 + (t - 8) * 4 + 3], v.w);
    }
}

// z[g][c] = zsum[g][c]/npg + b2[c]
__global__ __launch_bounds__(256)
void zred_kernel(const float* __restrict__ zsum, const float* __restrict__ b2,
                 const int* __restrict__ npg_p, float* __restrict__ Z, int n) {
    int npg = npg_p[0];
    int G = n / npg;
    float inv = 1.0f / (float)npg;
    for (int i = blockIdx.x * 256 + threadIdx.x; i < G * 32; i += gridDim.x * 256)
        Z[i] = zsum[i] * inv + b2[i & 31];
}

// Decoder fused: z gather weighted by fp16 dis[src]; inner += dis[node]*Z[g_i];
// acc = dis[node]*inner; dense phases register-blocked; t4h = fp16(dis*t4).
__global__ __launch_bounds__(256)
void dec1v4_kernel(const float* __restrict__ Z, const float* __restrict__ dis,
                   const int* __restrict__ off, const int* __restrict__ ew4,
                   const __half* __restrict__ diss,
                   const int* __restrict__ npg_p, const float* __restrict__ W3,
                   const float* __restrict__ b3, const float* __restrict__ W4,
                   __half* __restrict__ t4h, int n) {
    __shared__ float zacc[32 * 36];   // stride 36 (float4-aligned)
    __shared__ float hl[32 * 68];     // stride 68 (float4-aligned)
    int t = threadIdx.x;
    int npg = npg_p[0];
    float inv = 1.0f / (float)npg;
    int q = t & 7, ln = t >> 3;          // 8 lanes/node, 32 nodes/block
    int base = blockIdx.x * 32;
    int node = base + ln;
    const float4* zp = (const float4*)Z;

    float4 acc = make_float4(0.f, 0.f, 0.f, 0.f);
    if (node < n) {
        float dnode = dis[node];
        int gi = gdiv(node, npg, inv);
        float4 v = zp[(size_t)gi * 8 + q];
        acc.x = dnode * v.x; acc.y = dnode * v.y;
        acc.z = dnode * v.z; acc.w = dnode * v.w;
        acc = zedge_loop(zp, ew4, diss, off[node], off[node + 1], q, acc);
        acc.x *= dnode; acc.y *= dnode; acc.z *= dnode; acc.w *= dnode;
    }
    zacc[ln * 36 + q * 4 + 0] = acc.x;
    zacc[ln * 36 + q * 4 + 1] = acc.y;
    zacc[ln * 36 + q * 4 + 2] = acc.z;
    zacc[ln * 36 + q * 4 + 3] = acc.w;
    __syncthreads();

    // B1: h = relu(zacc @ W3 + b3). 64 cols x 4 row-groups of 8 nodes.
    {
        int j = t & 63;
        int i0 = (t >> 6) * 8;
        float w3c[32];
#pragma unroll
        for (int k = 0; k < 32; ++k) w3c[k] = W3[k * 64 + j];
        float bj = b3[j];
        const float4* za4 = (const float4*)zacc;
#pragma unroll
        for (int ii = 0; ii < 8; ++ii) {
            int i = i0 + ii;
            float s = bj;
#pragma unroll
            for (int m = 0; m < 8; ++m) {
                float4 zv = za4[i * 9 + m];
                s += zv.x * w3c[4 * m] + zv.y * w3c[4 * m + 1]
                   + zv.z * w3c[4 * m + 2] + zv.w * w3c[4 * m + 3];
            }
            hl[i * 68 + j] = fmaxf(s, 0.f);
        }
    }
    __syncthreads();

    // B2: t4h = dis * (hl @ W4) (64->16), fp16 store. 2 nodes/thread.
    {
        int c = t & 15;
        int i0 = t >> 4;
        int i1 = i0 + 16;
        const float4* hl4 = (const float4*)hl;
        float s0 = 0.f, s1 = 0.f;
#pragma unroll
        for (int kh = 0; kh < 2; ++kh) {
            float w4c[32];
#pragma unroll
            for (int k = 0; k < 32; ++k) w4c[k] = W4[(kh * 32 + k) * 16 + c];
#pragma unroll
            for (int m = 0; m < 8; ++m) {
                float4 h0 = hl4[i0 * 17 + kh * 8 + m];
                float4 h1 = hl4[i1 * 17 + kh * 8 + m];
                s0 += h0.x * w4c[4 * m] + h0.y * w4c[4 * m + 1]
                    + h0.z * w4c[4 * m + 2] + h0.w * w4c[4 * m + 3];
                s1 += h1.x * w4c[4 * m] + h1.y * w4c[4 * m + 1]
                    + h1.z * w4c[4 * m + 2] + h1.w * w4c[4 * m + 3];
            }
        }
        int nd0 = base + i0, nd1 = base + i1;
        if (nd0 < n) t4h[(size_t)nd0 * 16 + c] = __float2half(dis[nd0] * s0);
        if (nd1 < n) t4h[(size_t)nd1 * 16 + c] = __float2half(dis[nd1] * s1);
    }
}

extern "C" void kernel_launch(void* const* d_in, const int* in_sizes, int n_in,
                              void* d_out, int out_size, void* d_ws, size_t ws_size,
                              hipStream_t stream) {
    const float* x     = (const float*)d_in[0];
    const int*   ei    = (const int*)d_in[1];
    const int*   npg   = (const int*)d_in[3];
    const float* W1 = (const float*)d_in[4];
    const float* b1 = (const float*)d_in[5];
    const float* W2 = (const float*)d_in[6];
    const float* b2 = (const float*)d_in[7];
    const float* W3 = (const float*)d_in[8];
    const float* b3 = (const float*)d_in[9];
    const float* W4 = (const float*)d_in[10];
    const float* b4 = (const float*)d_in[11];
    float* out = (float*)d_out;

    int n = in_sizes[0] / 16;
    int E = in_sizes[1] / 2;
    const int* srcp = ei;
    const int* dstp = ei + E;

    char* w = (char*)d_ws;
    auto alloc = [&](size_t bytes) {
        char* p = w;
        w += (bytes + 255) & ~(size_t)255;
        return p;
    };
    float*  dis      = (float*)alloc((size_t)n * 4);
    int*    off      = (int*)alloc(((size_t)n + 1) * 4);
    int*    binned   = (int*)alloc((size_t)NBMAX * BCAP * 4);
    int*    ew4      = (int*)alloc((size_t)E * 4);
    __half* diss     = (__half*)alloc((size_t)E * 2);
    __half* disw     = (__half*)alloc((size_t)E * 2);
    h4*     xh       = (h4*)alloc((size_t)n * 16 * 2);
    __half* t2h      = (__half*)alloc((size_t)n * 32 * 2);
    __half* t4h      = (__half*)alloc((size_t)n * 16 * 2);
    float*  Z        = (float*)alloc((size_t)4096 * 32 * 4);
    float*  zsum     = (float*)alloc((size_t)4096 * 32 * 4);
    int*    bcnt     = (int*)alloc((size_t)NBMAX * 4);
    int*    lstart_g = (int*)alloc((size_t)NBMAX * BSZ * 4);
    int*    bstart_g = (int*)alloc((size_t)NBMAX * 4);

    int nbuck = (n + BSZ - 1) / BSZ;
    int nbin  = (E + ECHUNK - 1) / ECHUNK;

    // ---- CSR build + pre-scaled fp16 x table ----
    hipMemsetAsync(bcnt, 0, (size_t)NBMAX * 4, stream);
    hipMemsetAsync(zsum, 0, (size_t)4096 * 32 * 4, stream);
    binfill_kernel<<<nbin, 256, 0, stream>>>(srcp, dstp, bcnt, binned, E);
    csr_off_kernel<<<nbuck, 256, 0, stream>>>(binned, bcnt, off, dis, lstart_g, bstart_g, n, E);
    xconv_kernel<<<512, 256, 0, stream>>>(x, dis, xh, n * 4);
    bucket_scatter_kernel<<<nbuck, 256, 0, stream>>>(binned, bcnt, lstart_g, bstart_g,
                                                     dis, npg, ew4, diss, disw, n);

    // encode
    l1w2_kernel<<<(n + 63) / 64, 256, 0, stream>>>(xh, dis, off, ew4, W1, b1, W2, t2h, n);
    zagg_kernel<<<nbuck * ZSPLIT, 256, 0, stream>>>((const h4*)t2h, dis, off, ew4, disw, npg, zsum, n);
    zred_kernel<<<16, 256, 0, stream>>>(zsum, b2, npg, Z, n);

    // decode
    dec1v4_kernel<<<(n + 31) / 32, 256, 0, stream>>>(Z, dis, off, ew4, diss, npg, W3, b3, W4, t4h, n);
    agg16h_kernel<<<(n + 63) / 64, 256, 0, stream>>>((const h4*)t4h, dis, off, ew4, b4, out, n);
}

// Round 20
// 200.478 us; speedup vs baseline: 1.0748x; 1.0568x over previous
//
#include <hip/hip_runtime.h>
#include <hip/hip_bf16.h>
#include <hip/hip_fp16.h>

// ---------------------------------------------------------------------------
// GraphAutoEncoder: 4x GCNConv + mean-pool + repeat.
// R1-R10: CSR build via LDS-binned buckets; fused layer kernels; zagg fusion.
// R11-R14: dec1v4 dense phases register-blocked; l1w2 in simple 68-VGPR form.
// R15: gathered feature tables fp16 (xh/t2h/t4h); f32 weights+accum.
// R16: l1w2 h1 LDS in fp16 (occupancy 24->30%); scatter reuses csr_off's scan.
//      == BEST MEASURED CONFIG: 201 us ==
// R17: edge-split (dropped prefetch) REGRESSED 215 -> reverted.
// R18: weight factorization (4B ew + fp16 dis arrays) REGRESSED 212 — kernels
//      are LATENCY-bound, not fetch-bound; extra per-edge loads cost more
//      than the byte savings. -> reverted.
// R19: exact restore of the R16 configuration.
// ---------------------------------------------------------------------------

constexpr int BSZ_LOG = 9;                 // bucket = 512 dst nodes
constexpr int BSZ     = 1 << BSZ_LOG;
constexpr int NBMAX   = 256;               // max buckets (n <= 128K)
constexpr int ECHUNK  = 8192;              // edges per binfill block
constexpr int BCAP    = 12288;             // staging capacity per bucket
constexpr int ZSPLIT  = 8;                 // sub-blocks per bucket in zagg

struct alignas(8) h4 { __half2 a, b; };    // 4 halves = 8B

__device__ __forceinline__ float4 h4_to_f4(h4 v) {
    float2 fa = __half22float2(v.a), fb = __half22float2(v.b);
    return make_float4(fa.x, fa.y, fb.x, fb.y);
}

__device__ __forceinline__ int gdiv(int v, int npg, float inv) {
    int g = __float2int_rz((float)v * inv);
    int r = v - g * npg;
    if (r < 0) --g; else if (r >= npg) ++g;
    return g;
}

// Pass 1: LDS-binned bucket staging. code = (dst_local << 20) | src (src < 2^20).
__global__ __launch_bounds__(256)
void binfill_kernel(const int* __restrict__ src, const int* __restrict__ dst,
                    int* __restrict__ bcnt, int* __restrict__ binned, int E) {
    __shared__ int hist[NBMAX], hexcl[NBMAX], gbase[NBMAX], hpos[NBMAX], tmp[NBMAX];
    __shared__ int sorted[ECHUNK];
    __shared__ unsigned char bsorted[ECHUNK];
    int t = threadIdx.x;
    hist[t] = 0; hpos[t] = 0;
    __syncthreads();
    int e0 = blockIdx.x * ECHUNK;
    int cnt = min(ECHUNK, E - e0);
    for (int i = t; i < cnt; i += 256)
        atomicAdd(&hist[dst[e0 + i] >> BSZ_LOG], 1);
    __syncthreads();
    tmp[t] = hist[t];
    __syncthreads();
    for (int d = 1; d < 256; d <<= 1) {
        int v = (t >= d) ? tmp[t - d] : 0;
        __syncthreads();
        tmp[t] += v;
        __syncthreads();
    }
    hexcl[t] = (t == 0) ? 0 : tmp[t - 1];
    int h = hist[t];
    gbase[t] = (h > 0) ? atomicAdd(&bcnt[t], h) : 0;
    __syncthreads();
    for (int i = t; i < cnt; i += 256) {
        int s = src[e0 + i], d = dst[e0 + i];
        int b = d >> BSZ_LOG;
        int code = ((d & (BSZ - 1)) << 20) | s;
        int sp = hexcl[b] + atomicAdd(&hpos[b], 1);
        sorted[sp] = code;
        bsorted[sp] = (unsigned char)b;
    }
    __syncthreads();
    for (int i = t; i < cnt; i += 256) {
        int b = bsorted[i];
        binned[(size_t)b * BCAP + gbase[b] + (i - hexcl[b])] = sorted[i];
    }
}

// Block-reduce sum of bcnt[0..b) -> returned in sums[0] (all threads see it).
__device__ __forceinline__ int prefix_before(const int* __restrict__ bcnt,
                                             int b, int* sums) {
    int t = threadIdx.x;
    sums[t] = (t < b) ? bcnt[t] : 0;
    __syncthreads();
    for (int d = 128; d > 0; d >>= 1) {
        if (t < d) sums[t] += sums[t + d];
        __syncthreads();
    }
    int r = sums[0];
    __syncthreads();
    return r;
}

// Per bucket: LDS node histogram + scan -> off[]/dis[]; persists lstart/bstart.
__global__ __launch_bounds__(256)
void csr_off_kernel(const int* __restrict__ binned, const int* __restrict__ bcnt,
                    int* __restrict__ off, float* __restrict__ dis,
                    int* __restrict__ lstart_g, int* __restrict__ bstart_g,
                    int n, int E) {
    __shared__ int hist[BSZ];
    __shared__ int lstart[BSZ];
    __shared__ int partial[256];
    int b = blockIdx.x, t = threadIdx.x;
    int nb0 = b << BSZ_LOG;
    int nn = min(BSZ, n - nb0);
    int m = bcnt[b];
    int bs = prefix_before(bcnt, b, partial);
    const int* bp = binned + (size_t)b * BCAP;
    for (int i = t; i < BSZ; i += 256) hist[i] = 0;
    __syncthreads();
    for (int i = t; i < m; i += 256)
        atomicAdd(&hist[bp[i] >> 20], 1);
    __syncthreads();
    int a0 = hist[2 * t], a1 = hist[2 * t + 1];
    partial[t] = a0 + a1;
    __syncthreads();
    for (int d = 1; d < 256; d <<= 1) {
        int v = (t >= d) ? partial[t - d] : 0;
        __syncthreads();
        partial[t] += v;
        __syncthreads();
    }
    int base = (t == 0) ? 0 : partial[t - 1];
    lstart[2 * t] = base;
    lstart[2 * t + 1] = base + a0;
    __syncthreads();
    for (int i = t; i < BSZ; i += 256)
        lstart_g[(b << BSZ_LOG) + i] = lstart[i];
    for (int i = t; i < nn; i += 256) {
        off[nb0 + i] = bs + lstart[i];
        dis[nb0 + i] = rsqrtf((float)hist[i] + 1.0f);   // +1 = self-loop
    }
    if (t == 0) bstart_g[b] = bs;
    if (b == 0 && t == 0) off[n] = E;
}

// Per bucket: scatter {src | g<<20, w} using the persisted lstart/bstart.
__global__ __launch_bounds__(256)
void bucket_scatter_kernel(const int* __restrict__ binned, const int* __restrict__ bcnt,
                           const int* __restrict__ lstart_g, const int* __restrict__ bstart_g,
                           const float* __restrict__ dis,
                           const int* __restrict__ npg_p, int2* __restrict__ ew, int n) {
    __shared__ int lstart[BSZ];
    __shared__ int lpos[BSZ];
    __shared__ float ldis[BSZ];
    int b = blockIdx.x, t = threadIdx.x;
    int nb0 = b << BSZ_LOG;
    int nn = min(BSZ, n - nb0);
    int m = bcnt[b];
    int e0 = bstart_g[b];
    int npg = npg_p[0];
    float inv = 1.0f / (float)npg;
    const int* bp = binned + (size_t)b * BCAP;
    for (int i = t; i < BSZ; i += 256) {
        lstart[i] = lstart_g[(b << BSZ_LOG) + i];
        lpos[i] = 0;
        ldis[i] = (i < nn) ? dis[nb0 + i] : 0.f;
    }
    __syncthreads();
    for (int i = t; i < m; i += 256) {
        int code = bp[i];
        int dl = code >> 20, s = code & 0xFFFFF;
        float w = dis[s] * ldis[dl];
        int g = gdiv(s, npg, inv);
        int p = e0 + lstart[dl] + atomicAdd(&lpos[dl], 1);
        ew[p] = make_int2(s | (g << 20), __float_as_int(w));
    }
}

// x (f32, n x 16) -> xh (fp16). One float4 -> h4 per thread, grid-stride.
__global__ __launch_bounds__(256)
void xconv_kernel(const float* __restrict__ x, h4* __restrict__ xh, int n4) {
    const float4* xp = (const float4*)x;
    for (int i = blockIdx.x * 256 + threadIdx.x; i < n4; i += gridDim.x * 256) {
        float4 v = xp[i];
        h4 o;
        o.a = __floats2half2_rn(v.x, v.y);
        o.b = __floats2half2_rn(v.z, v.w);
        xh[i] = o;
    }
}

// ---- shfl-broadcast edge-gather core over fp16 tables (TPN lanes/node) ----
template <int TPN, bool USE_G>
__device__ __forceinline__ float4
edge_loop_h(const h4* __restrict__ hp, const int2* __restrict__ ew,
            int e0, int e1, int q, float4 acc) {
    int deg = e1 - e0;
    int nfull = deg / TPN;
    int r = deg - nfull * TPN;
    int idx = e0 + q;
    int2 a = make_int2(0, 0);
    if (idx < e1) a = ew[idx];
    for (int c = 0; c < nfull; ++c) {
        int nidx = idx + (c + 1) * TPN;
        int2 an = make_int2(0, 0);
        if (nidx < e1) an = ew[nidx];
#pragma unroll
        for (int k = 0; k < TPN; ++k) {
            int ax = __shfl(a.x, k, TPN);
            float w = __int_as_float(__shfl(a.y, k, TPN));
            int row = USE_G ? (int)(((unsigned)ax) >> 20) : (ax & 0xFFFFF);
            float4 v = h4_to_f4(hp[(size_t)row * TPN + q]);
            acc.x += w * v.x; acc.y += w * v.y; acc.z += w * v.z; acc.w += w * v.w;
        }
        a = an;
    }
    for (int k = 0; k < r; ++k) {
        int ax = __shfl(a.x, k, TPN);
        float w = __int_as_float(__shfl(a.y, k, TPN));
        int row = USE_G ? (int)(((unsigned)ax) >> 20) : (ax & 0xFFFFF);
        float4 v = h4_to_f4(hp[(size_t)row * TPN + q]);
        acc.x += w * v.x; acc.y += w * v.y; acc.z += w * v.z; acc.w += w * v.w;
    }
    return acc;
}

// f32-table variant (dec1v4's z gather).
template <int TPN, bool USE_G>
__device__ __forceinline__ float4
edge_loop(const float4* __restrict__ hp, const int2* __restrict__ ew,
          int e0, int e1, int q, float4 acc) {
    int deg = e1 - e0;
    int nfull = deg / TPN;
    int r = deg - nfull * TPN;
    int idx = e0 + q;
    int2 a = make_int2(0, 0);
    if (idx < e1) a = ew[idx];
    for (int c = 0; c < nfull; ++c) {
        int nidx = idx + (c + 1) * TPN;
        int2 an = make_int2(0, 0);
        if (nidx < e1) an = ew[nidx];
#pragma unroll
        for (int k = 0; k < TPN; ++k) {
            int ax = __shfl(a.x, k, TPN);
            float w = __int_as_float(__shfl(a.y, k, TPN));
            int row = USE_G ? (int)(((unsigned)ax) >> 20) : (ax & 0xFFFFF);
            float4 v = hp[(size_t)row * TPN + q];
            acc.x += w * v.x; acc.y += w * v.y; acc.z += w * v.z; acc.w += w * v.w;
        }
        a = an;
    }
    for (int k = 0; k < r; ++k) {
        int ax = __shfl(a.x, k, TPN);
        float w = __int_as_float(__shfl(a.y, k, TPN));
        int row = USE_G ? (int)(((unsigned)ax) >> 20) : (ax & 0xFFFFF);
        float4 v = hp[(size_t)row * TPN + q];
        acc.x += w * v.x; acc.y += w * v.y; acc.z += w * v.z; acc.w += w * v.w;
    }
    return acc;
}

// Layer 1 + W2 fused: agg xh (fp16, f32 accum); phase-B h1 into LDS (fp16);
// phase-C t2h to global. Simple form — do NOT register-block this kernel.
__global__ __launch_bounds__(256)
void l1w2_kernel(const h4* __restrict__ xh, const float* __restrict__ dis,
                 const int* __restrict__ off, const int2* __restrict__ ew,
                 const float* __restrict__ W1, const float* __restrict__ b1,
                 const float* __restrict__ W2, __half* __restrict__ t2h, int n) {
    __shared__ float accs[64][17];
    __shared__ __half2 hlh[64][33];   // 64 halves/row + pad (odd half2 stride)
    __shared__ float Wl[16 * 64];
    __shared__ float bl[64];
    int t = threadIdx.x;
    for (int i = t; i < 16 * 64; i += 256) Wl[i] = W1[i];
    if (t < 64) bl[t] = b1[t];

    int q = t & 3, ln = t >> 2;
    int node = blockIdx.x * 64 + ln;
    float4 acc = make_float4(0.f, 0.f, 0.f, 0.f);
    if (node < n) {
        float di = dis[node], d2 = di * di;
        float4 v = h4_to_f4(xh[(size_t)node * 4 + q]);
        acc.x = d2 * v.x; acc.y = d2 * v.y; acc.z = d2 * v.z; acc.w = d2 * v.w;
        acc = edge_loop_h<4, false>(xh, ew, off[node], off[node + 1], q, acc);
    }
    accs[ln][q * 4 + 0] = acc.x; accs[ln][q * 4 + 1] = acc.y;
    accs[ln][q * 4 + 2] = acc.z; accs[ln][q * 4 + 3] = acc.w;
    __syncthreads();

    // Phase B: h1 row (64-wide) into LDS as fp16.
    int j = t & 63;
    for (int nb = (t >> 6); nb < 64; nb += 4) {
        float s = bl[j];
#pragma unroll
        for (int k = 0; k < 16; ++k) s += accs[nb][k] * Wl[k * 64 + j];
        ((__half*)hlh[nb])[j] = __float2half(fmaxf(s, 0.f));
    }
    __syncthreads();

    // Phase C: t2h[node][c] = h1 . W2[:,c]  (h1 fp16 pairs from LDS)
    int base = blockIdx.x * 64;
    int c = t & 31;
    for (int nb = (t >> 5); nb < 64; nb += 8) {
        int nd = base + nb;
        if (nd >= n) break;
        float s = 0.f;
#pragma unroll
        for (int k = 0; k < 32; ++k) {
            float2 hp = __half22float2(hlh[nb][k]);
            s += hp.x * W2[(2 * k) * 32 + c] + hp.y * W2[(2 * k + 1) * 32 + c];
        }
        t2h[(size_t)nd * 32 + c] = __float2half(s);
    }
}

// Final aggregate: t4h (fp16 table) through CSR, +b4, write f32 out.
__global__ __launch_bounds__(256)
void agg16h_kernel(const h4* __restrict__ t4h, const float* __restrict__ dis,
                   const int* __restrict__ off, const int2* __restrict__ ew,
                   const float* __restrict__ b, float* __restrict__ out, int n) {
    int t = threadIdx.x;
    int q = t & 3, ln = t >> 2;
    int node = blockIdx.x * 64 + ln;
    if (node >= n) return;
    float di = dis[node], d2 = di * di;
    float4 v = h4_to_f4(t4h[(size_t)node * 4 + q]);
    float4 acc;
    acc.x = d2 * v.x; acc.y = d2 * v.y; acc.z = d2 * v.z; acc.w = d2 * v.w;
    acc = edge_loop_h<4, false>(t4h, ew, off[node], off[node + 1], q, acc);
    float4 bb = ((const float4*)b)[q];
    float4 o;
    o.x = acc.x + bb.x; o.y = acc.y + bb.y; o.z = acc.z + bb.z; o.w = acc.w + bb.w;
    ((float4*)out)[(size_t)node * 4 + q] = o;
}

// zagg: per (bucket, split): accumulate z-sums edge-major from t2h (fp16).
__global__ __launch_bounds__(256)
void zagg_kernel(const h4* __restrict__ t2h, const float* __restrict__ dis,
                 const int* __restrict__ off, const int2* __restrict__ ew,
                 const int* __restrict__ npg_p, float* __restrict__ zsum, int n) {
    __shared__ float4 red0[256];
    __shared__ float4 red1[256];
    int blk = blockIdx.x;
    int b = blk / ZSPLIT, s = blk % ZSPLIT;
    int t = threadIdx.x, q = t & 7, r = t >> 3;
    int npg = npg_p[0];
    int nb0 = b << BSZ_LOG;
    int nn = min(BSZ, n - nb0);
    int g0 = nb0 / npg;
    int nodeB = min((g0 + 1) * npg - nb0, nn);   // local boundary node
    int e0 = off[nb0], e1 = off[nb0 + nn];
    int P  = off[nb0 + nodeB];
    int m = e1 - e0;

    float4 a0 = make_float4(0.f, 0.f, 0.f, 0.f);
    float4 a1 = make_float4(0.f, 0.f, 0.f, 0.f);
    int i0 = (int)((long long)m * s / ZSPLIT);
    int i1 = (int)((long long)m * (s + 1) / ZSPLIT);
    for (int i = i0 + r; i < i1; i += 32) {
        int e = e0 + i;
        int2 aa = ew[e];
        float w = __int_as_float(aa.y);
        int src = aa.x & 0xFFFFF;
        float4 v = h4_to_f4(t2h[(size_t)src * 8 + q]);
        if (e < P) {
            a0.x += w * v.x; a0.y += w * v.y; a0.z += w * v.z; a0.w += w * v.w;
        } else {
            a1.x += w * v.x; a1.y += w * v.y; a1.z += w * v.z; a1.w += w * v.w;
        }
    }
    int j0 = nn * s / ZSPLIT, j1 = nn * (s + 1) / ZSPLIT;
    for (int i = j0 + r; i < j1; i += 32) {
        int node = nb0 + i;
        float di = dis[node], d2 = di * di;
        float4 v = h4_to_f4(t2h[(size_t)node * 8 + q]);
        if (i < nodeB) {
            a0.x += d2 * v.x; a0.y += d2 * v.y; a0.z += d2 * v.z; a0.w += d2 * v.w;
        } else {
            a1.x += d2 * v.x; a1.y += d2 * v.y; a1.z += d2 * v.z; a1.w += d2 * v.w;
        }
    }
    red0[t] = a0; red1[t] = a1;
    __syncthreads();
    for (int d = 128; d >= 8; d >>= 1) {
        if (t < d) {
            float4 u = red0[t], v = red0[t + d];
            u.x += v.x; u.y += v.y; u.z += v.z; u.w += v.w;
            red0[t] = u;
            u = red1[t]; v = red1[t + d];
            u.x += v.x; u.y += v.y; u.z += v.z; u.w += v.w;
            red1[t] = u;
        }
        __syncthreads();
    }
    if (t < 8) {
        float4 v = red0[t];
        atomicAdd(&zsum[g0 * 32 + t * 4 + 0], v.x);
        atomicAdd(&zsum[g0 * 32 + t * 4 + 1], v.y);
        atomicAdd(&zsum[g0 * 32 + t * 4 + 2], v.z);
        atomicAdd(&zsum[g0 * 32 + t * 4 + 3], v.w);
    } else if (t < 16 && nodeB < nn) {
        float4 v = red1[t - 8];
        atomicAdd(&zsum[(g0 + 1) * 32 + (t - 8) * 4 + 0], v.x);
        atomicAdd(&zsum[(g0 + 1) * 32 + (t - 8) * 4 + 1], v.y);
        atomicAdd(&zsum[(g0 + 1) * 32 + (t - 8) * 4 + 2], v.z);
        atomicAdd(&zsum[(g0 + 1) * 32 + (t - 8) * 4 + 3], v.w);
    }
}

// z[g][c] = zsum[g][c]/npg + b2[c]
__global__ __launch_bounds__(256)
void zred_kernel(const float* __restrict__ zsum, const float* __restrict__ b2,
                 const int* __restrict__ npg_p, float* __restrict__ Z, int n) {
    int npg = npg_p[0];
    int G = n / npg;
    float inv = 1.0f / (float)npg;
    for (int i = blockIdx.x * 256 + threadIdx.x; i < G * 32; i += gridDim.x * 256)
        Z[i] = zsum[i] * inv + b2[i & 31];
}

// Decoder fused: aggregate 32-wide z rows (f32, L1-resident); dense phases
// register-blocked; writes t4h (fp16) for the final aggregation.
__global__ __launch_bounds__(256)
void dec1v4_kernel(const float* __restrict__ Z, const float* __restrict__ dis,
                   const int* __restrict__ off, const int2* __restrict__ ew,
                   const int* __restrict__ npg_p, const float* __restrict__ W3,
                   const float* __restrict__ b3, const float* __restrict__ W4,
                   __half* __restrict__ t4h, int n) {
    __shared__ float zacc[32 * 36];   // stride 36 (float4-aligned)
    __shared__ float hl[32 * 68];     // stride 68 (float4-aligned)
    int t = threadIdx.x;
    int npg = npg_p[0];
    float inv = 1.0f / (float)npg;
    int q = t & 7, ln = t >> 3;          // 8 lanes/node, 32 nodes/block
    int base = blockIdx.x * 32;
    int node = base + ln;
    const float4* zp = (const float4*)Z;

    float4 acc = make_float4(0.f, 0.f, 0.f, 0.f);
    if (node < n) {
        float di = dis[node], d2 = di * di;
        int gi = gdiv(node, npg, inv);
        float4 v = zp[(size_t)gi * 8 + q];
        acc.x = d2 * v.x; acc.y = d2 * v.y; acc.z = d2 * v.z; acc.w = d2 * v.w;
        acc = edge_loop<8, true>(zp, ew, off[node], off[node + 1], q, acc);
    }
    zacc[ln * 36 + q * 4 + 0] = acc.x;
    zacc[ln * 36 + q * 4 + 1] = acc.y;
    zacc[ln * 36 + q * 4 + 2] = acc.z;
    zacc[ln * 36 + q * 4 + 3] = acc.w;
    __syncthreads();

    // B1: h = relu(zacc @ W3 + b3). 64 cols x 4 row-groups of 8 nodes.
    {
        int j = t & 63;
        int i0 = (t >> 6) * 8;
        float w3c[32];
#pragma unroll
        for (int k = 0; k < 32; ++k) w3c[k] = W3[k * 64 + j];
        float bj = b3[j];
        const float4* za4 = (const float4*)zacc;
#pragma unroll
        for (int ii = 0; ii < 8; ++ii) {
            int i = i0 + ii;
            float s = bj;
#pragma unroll
            for (int m = 0; m < 8; ++m) {
                float4 zv = za4[i * 9 + m];
                s += zv.x * w3c[4 * m] + zv.y * w3c[4 * m + 1]
                   + zv.z * w3c[4 * m + 2] + zv.w * w3c[4 * m + 3];
            }
            hl[i * 68 + j] = fmaxf(s, 0.f);
        }
    }
    __syncthreads();

    // B2: t4h = hl @ W4 (64->16), fp16 store. 16 cols x 16 rows; 2 nodes/thread.
    {
        int c = t & 15;
        int i0 = t >> 4;
        int i1 = i0 + 16;
        const float4* hl4 = (const float4*)hl;
        float s0 = 0.f, s1 = 0.f;
#pragma unroll
        for (int kh = 0; kh < 2; ++kh) {
            float w4c[32];
#pragma unroll
            for (int k = 0; k < 32; ++k) w4c[k] = W4[(kh * 32 + k) * 16 + c];
#pragma unroll
            for (int m = 0; m < 8; ++m) {
                float4 h0 = hl4[i0 * 17 + kh * 8 + m];
                float4 h1 = hl4[i1 * 17 + kh * 8 + m];
                s0 += h0.x * w4c[4 * m] + h0.y * w4c[4 * m + 1]
                    + h0.z * w4c[4 * m + 2] + h0.w * w4c[4 * m + 3];
                s1 += h1.x * w4c[4 * m] + h1.y * w4c[4 * m + 1]
                    + h1.z * w4c[4 * m + 2] + h1.w * w4c[4 * m + 3];
            }
        }
        int nd0 = base + i0, nd1 = base + i1;
        if (nd0 < n) t4h[(size_t)nd0 * 16 + c] = __float2half(s0);
        if (nd1 < n) t4h[(size_t)nd1 * 16 + c] = __float2half(s1);
    }
}

extern "C" void kernel_launch(void* const* d_in, const int* in_sizes, int n_in,
                              void* d_out, int out_size, void* d_ws, size_t ws_size,
                              hipStream_t stream) {
    const float* x     = (const float*)d_in[0];
    const int*   ei    = (const int*)d_in[1];
    const int*   npg   = (const int*)d_in[3];
    const float* W1 = (const float*)d_in[4];
    const float* b1 = (const float*)d_in[5];
    const float* W2 = (const float*)d_in[6];
    const float* b2 = (const float*)d_in[7];
    const float* W3 = (const float*)d_in[8];
    const float* b3 = (const float*)d_in[9];
    const float* W4 = (const float*)d_in[10];
    const float* b4 = (const float*)d_in[11];
    float* out = (float*)d_out;

    int n = in_sizes[0] / 16;
    int E = in_sizes[1] / 2;
    const int* srcp = ei;
    const int* dstp = ei + E;

    char* w = (char*)d_ws;
    auto alloc = [&](size_t bytes) {
        char* p = w;
        w += (bytes + 255) & ~(size_t)255;
        return p;
    };
    float*  dis      = (float*)alloc((size_t)n * 4);
    int*    off      = (int*)alloc(((size_t)n + 1) * 4);
    int*    binned   = (int*)alloc((size_t)NBMAX * BCAP * 4);
    int2*   ew       = (int2*)alloc((size_t)E * 8);
    h4*     xh       = (h4*)alloc((size_t)n * 16 * 2);
    __half* t2h      = (__half*)alloc((size_t)n * 32 * 2);
    __half* t4h      = (__half*)alloc((size_t)n * 16 * 2);
    float*  Z        = (float*)alloc((size_t)4096 * 32 * 4);
    float*  zsum     = (float*)alloc((size_t)4096 * 32 * 4);
    int*    bcnt     = (int*)alloc((size_t)NBMAX * 4);
    int*    lstart_g = (int*)alloc((size_t)NBMAX * BSZ * 4);
    int*    bstart_g = (int*)alloc((size_t)NBMAX * 4);

    int nbuck = (n + BSZ - 1) / BSZ;
    int nbin  = (E + ECHUNK - 1) / ECHUNK;

    // ---- CSR build + fp16 x table ----
    hipMemsetAsync(bcnt, 0, (size_t)NBMAX * 4, stream);
    hipMemsetAsync(zsum, 0, (size_t)4096 * 32 * 4, stream);
    xconv_kernel<<<512, 256, 0, stream>>>(x, xh, n * 4);
    binfill_kernel<<<nbin, 256, 0, stream>>>(srcp, dstp, bcnt, binned, E);
    csr_off_kernel<<<nbuck, 256, 0, stream>>>(binned, bcnt, off, dis, lstart_g, bstart_g, n, E);
    bucket_scatter_kernel<<<nbuck, 256, 0, stream>>>(binned, bcnt, lstart_g, bstart_g, dis, npg, ew, n);

    // encode
    l1w2_kernel<<<(n + 63) / 64, 256, 0, stream>>>(xh, dis, off, ew, W1, b1, W2, t2h, n);
    zagg_kernel<<<nbuck * ZSPLIT, 256, 0, stream>>>((const h4*)t2h, dis, off, ew, npg, zsum, n);
    zred_kernel<<<16, 256, 0, stream>>>(zsum, b2, npg, Z, n);

    // decode
    dec1v4_kernel<<<(n + 31) / 32, 256, 0, stream>>>(Z, dis, off, ew, npg, W3, b3, W4, t4h, n);
    agg16h_kernel<<<(n + 63) / 64, 256, 0, stream>>>((const h4*)t4h, dis, off, ew, b4, out, n);
}